// Round 1
// baseline (1455.248 us; speedup 1.0000x reference)
//
#include <hip/hip_runtime.h>

#define S_ 512
#define B_ 64
#define V_ 50000
#define E_ 300
#define H_ 256
#define C_ 5

// ---------------------------------------------------------------------------
// fast tanh: tanh(x) = (e^{2x}-1)/(e^{2x}+1), e^{2x} = 2^{2x*log2(e)}
// clamp so exp2 never overflows (tanh saturates in fp32 far before |x|=9.5)
// ---------------------------------------------------------------------------
__device__ __forceinline__ float fast_tanh(float x) {
    x = fminf(9.5f, fmaxf(-9.5f, x));
    float e = __builtin_amdgcn_exp2f(x * 2.88539008177793f);  // 2*log2(e)
    return (e - 1.0f) * __builtin_amdgcn_rcpf(e + 1.0f);
}

// ---------------------------------------------------------------------------
// Kernel A: transpose W_ih (H,E) -> WT (E,H) so the GEMM's weight loads are
// coalesced across the h-threads.
// ---------------------------------------------------------------------------
__global__ void transpose_kernel(const float* __restrict__ W_ih,
                                 float* __restrict__ WT) {
    int i = blockIdx.x * 256 + threadIdx.x;
    if (i < E_ * H_) {
        int e = i / H_;
        int h = i - e * H_;
        WT[i] = W_ih[h * E_ + e];
    }
}

// ---------------------------------------------------------------------------
// Kernel B: xw[s,b,h] = sum_e emb[idx[s,b],e]*W_ih[h,e] + b_ih[h] + b_hh[h]
// 512 blocks x 256 threads; each block does 64 (s,b) rows.
// Embedding rows staged in LDS (75 KB); x reads are uniform-address
// broadcasts; WT reads are coalesced and L2-hot.
// ---------------------------------------------------------------------------
__global__ __launch_bounds__(256) void xw_kernel(
    const int* __restrict__ idx, const float* __restrict__ emb,
    const float* __restrict__ WT, const float* __restrict__ b_ih,
    const float* __restrict__ b_hh, float* __restrict__ xw) {
    __shared__ float xs[64 * E_];  // 76800 B
    const int base = blockIdx.x * 64;
    const int tid = threadIdx.x;

    for (int t = tid; t < 64 * E_; t += 256) {
        int r = t / E_;
        int e = t - r * E_;
        xs[t] = emb[(size_t)idx[base + r] * E_ + e];
    }
    __syncthreads();

    const int h = tid;
    float acc[64];
#pragma unroll
    for (int r = 0; r < 64; ++r) acc[r] = 0.0f;

    for (int e = 0; e < E_; e += 4) {  // 300 = 75*4
        float w0 = WT[(e + 0) * H_ + h];
        float w1 = WT[(e + 1) * H_ + h];
        float w2 = WT[(e + 2) * H_ + h];
        float w3 = WT[(e + 3) * H_ + h];
#pragma unroll
        for (int r = 0; r < 64; ++r) {
            const float4 xv = *(const float4*)(xs + r * E_ + e);
            acc[r] = fmaf(xv.w, w3,
                     fmaf(xv.z, w2, fmaf(xv.y, w1, fmaf(xv.x, w0, acc[r]))));
        }
    }

    const float bias = b_ih[h] + b_hh[h];
#pragma unroll 4
    for (int r = 0; r < 64; ++r) {
        xw[(size_t)(base + r) * H_ + h] = acc[r] + bias;
    }
}

// ---------------------------------------------------------------------------
// Kernel C: the sequential recurrence. One block per batch element.
// Thread i holds row i of W_hh in 256 VGPRs (64 float4). h double-buffered
// in LDS; all h reads are uniform-address broadcasts (conflict-free).
// One barrier per step. xw for step s+1 prefetched during step s.
// Accumulates hsum[i] = sum_s h_s[i] in a register (epilogue algebra).
// ---------------------------------------------------------------------------
__global__ __launch_bounds__(256, 1) void rnn_kernel(
    const float* __restrict__ xw, const float* __restrict__ W_hh,
    float* __restrict__ hsum_out) {
    const int b = blockIdx.x;
    const int i = threadIdx.x;

    __shared__ float hbuf[2][H_];

    float4 w[H_ / 4];
    const float4* wrow = (const float4*)(W_hh + (size_t)i * H_);
#pragma unroll
    for (int q = 0; q < H_ / 4; ++q) w[q] = wrow[q];

    hbuf[0][i] = 0.0f;
    float hs = 0.0f;
    __syncthreads();

    int cur = 0;
    float xw_next = xw[(size_t)b * H_ + i];  // s = 0 (biases already folded in)
    for (int s = 0; s < S_; ++s) {
        float pre = xw_next;  // waits on the load issued last iteration
        int sn = (s + 1 < S_) ? s + 1 : s;
        xw_next = xw[((size_t)sn * B_ + b) * H_ + i];  // prefetch next step

#pragma unroll
        for (int q = 0; q < H_ / 4; ++q) {
            const float4 hv = *(const float4*)&hbuf[cur][q * 4];
            pre = fmaf(w[q].x, hv.x, pre);
            pre = fmaf(w[q].y, hv.y, pre);
            pre = fmaf(w[q].z, hv.z, pre);
            pre = fmaf(w[q].w, hv.w, pre);
        }
        float hn = fast_tanh(pre);
        hs += hn;
        hbuf[cur ^ 1][i] = hn;
        __syncthreads();
        cur ^= 1;
    }
    hsum_out[b * H_ + i] = hs;
}

// ---------------------------------------------------------------------------
// Kernel D: summed logits = hsum @ W_out^T + S*b_out, then log_softmax.
// Tiny: 64 threads, one per batch element.
// ---------------------------------------------------------------------------
__global__ void out_kernel(const float* __restrict__ hsum,
                           const float* __restrict__ W_out,
                           const float* __restrict__ b_out,
                           float* __restrict__ out) {
    int b = threadIdx.x;
    if (b >= B_) return;
    float logits[C_];
#pragma unroll
    for (int c = 0; c < C_; ++c) {
        float acc = 0.0f;
        for (int k = 0; k < H_; ++k)
            acc = fmaf(hsum[b * H_ + k], W_out[c * H_ + k], acc);
        logits[c] = acc + (float)S_ * b_out[c];
    }
    float m = logits[0];
#pragma unroll
    for (int c = 1; c < C_; ++c) m = fmaxf(m, logits[c]);
    float sum = 0.0f;
#pragma unroll
    for (int c = 0; c < C_; ++c) sum += expf(logits[c] - m);
    float lse = logf(sum);
#pragma unroll
    for (int c = 0; c < C_; ++c) out[b * C_ + c] = logits[c] - m - lse;
}

// ---------------------------------------------------------------------------
extern "C" void kernel_launch(void* const* d_in, const int* in_sizes, int n_in,
                              void* d_out, int out_size, void* d_ws,
                              size_t ws_size, hipStream_t stream) {
    const int* idx = (const int*)d_in[0];
    const float* emb = (const float*)d_in[1];
    const float* W_ih = (const float*)d_in[2];
    const float* W_hh = (const float*)d_in[3];
    const float* b_ih = (const float*)d_in[4];
    const float* b_hh = (const float*)d_in[5];
    const float* W_out = (const float*)d_in[6];
    const float* b_out = (const float*)d_in[7];
    float* out = (float*)d_out;

    float* ws = (float*)d_ws;
    float* WT = ws;                                 // E*H      = 76800 floats
    float* xw = WT + E_ * H_;                       // S*B*H    = 8388608 floats
    float* hsum = xw + (size_t)S_ * B_ * H_;        // B*H      = 16384 floats
    // total ~33.9 MB of d_ws

    hipLaunchKernelGGL(transpose_kernel, dim3((E_ * H_ + 255) / 256), dim3(256),
                       0, stream, W_ih, WT);
    hipLaunchKernelGGL(xw_kernel, dim3((S_ * B_) / 64), dim3(256), 0, stream,
                       idx, emb, WT, b_ih, b_hh, xw);
    hipLaunchKernelGGL(rnn_kernel, dim3(B_), dim3(256), 0, stream, xw, W_hh,
                       hsum);
    hipLaunchKernelGGL(out_kernel, dim3(1), dim3(64), 0, stream, hsum, W_out,
                       b_out, out);
}

// Round 2
// 540.157 us; speedup vs baseline: 2.6941x; 2.6941x over previous
//
#include <hip/hip_runtime.h>

#define S_ 512
#define B_ 64
#define V_ 50000
#define E_ 300
#define H_ 256
#define C_ 5

// ---------------------------------------------------------------------------
// fast tanh: tanh(x) = (e^{2x}-1)/(e^{2x}+1), e^{2x} = 2^{2x*log2(e)}
// clamp so exp2 never overflows (tanh saturates in fp32 far before |x|=9.5)
// ---------------------------------------------------------------------------
__device__ __forceinline__ float fast_tanh(float x) {
    x = fminf(9.5f, fmaxf(-9.5f, x));
    float e = __builtin_amdgcn_exp2f(x * 2.88539008177793f);  // 2*log2(e)
    return (e - 1.0f) * __builtin_amdgcn_rcpf(e + 1.0f);
}

// ---------------------------------------------------------------------------
// Kernel A: transpose W_ih (H,E) -> WT (E,H) so the GEMM's weight loads are
// coalesced across the h-threads.
// ---------------------------------------------------------------------------
__global__ void transpose_kernel(const float* __restrict__ W_ih,
                                 float* __restrict__ WT) {
    int i = blockIdx.x * 256 + threadIdx.x;
    if (i < E_ * H_) {
        int e = i / H_;
        int h = i - e * H_;
        WT[i] = W_ih[h * E_ + e];
    }
}

// ---------------------------------------------------------------------------
// Kernel B: xw[s,b,h] = sum_e emb[idx[s,b],e]*W_ih[h,e] + b_ih[h] + b_hh[h]
// 512 blocks x 256 threads; each block does 64 (s,b) rows.
// ---------------------------------------------------------------------------
__global__ __launch_bounds__(256) void xw_kernel(
    const int* __restrict__ idx, const float* __restrict__ emb,
    const float* __restrict__ WT, const float* __restrict__ b_ih,
    const float* __restrict__ b_hh, float* __restrict__ xw) {
    __shared__ float xs[64 * E_];  // 76800 B
    const int base = blockIdx.x * 64;
    const int tid = threadIdx.x;

    for (int t = tid; t < 64 * E_; t += 256) {
        int r = t / E_;
        int e = t - r * E_;
        xs[t] = emb[(size_t)idx[base + r] * E_ + e];
    }
    __syncthreads();

    const int h = tid;
    float acc[64];
#pragma unroll
    for (int r = 0; r < 64; ++r) acc[r] = 0.0f;

    for (int e = 0; e < E_; e += 4) {  // 300 = 75*4
        float w0 = WT[(e + 0) * H_ + h];
        float w1 = WT[(e + 1) * H_ + h];
        float w2 = WT[(e + 2) * H_ + h];
        float w3 = WT[(e + 3) * H_ + h];
#pragma unroll
        for (int r = 0; r < 64; ++r) {
            const float4 xv = *(const float4*)(xs + r * E_ + e);
            acc[r] = fmaf(xv.w, w3,
                     fmaf(xv.z, w2, fmaf(xv.y, w1, fmaf(xv.x, w0, acc[r]))));
        }
    }

    const float bias = b_ih[h] + b_hh[h];
#pragma unroll 4
    for (int r = 0; r < 64; ++r) {
        xw[(size_t)(base + r) * H_ + h] = acc[r] + bias;
    }
}

// ---------------------------------------------------------------------------
// Kernel C: sequential recurrence. One block of 1024 threads per batch
// element (16 waves -> 4 waves/SIMD for latency hiding).
//
// Output row i = tid>>2 is computed by the 4 lanes p = tid&3, which split
// K=256 four ways, INTERLEAVED by float4-chunk (chunk index 4q+p):
//   - weights per thread: 16 float4 = 64 VGPRs -> register-resident
//   - dependency chain per accumulator: 16 fma (4 independent accumulators)
//   - LDS read per (q): lanes p=0..3 read 4 consecutive 16B addresses
//     (64B total, 4 distinct bank-quads, broadcast x16) -> conflict-free,
//     address = base + 16p + 64q with compile-time 64q offset.
// Partials combined with 2x __shfl_xor within the 4-lane group.
// One barrier per step; h double-buffered in LDS; xw prefetched.
// ---------------------------------------------------------------------------
__global__ __launch_bounds__(1024, 1) void rnn_kernel(
    const float* __restrict__ xw, const float* __restrict__ W_hh,
    float* __restrict__ hsum_out) {
    const int b = blockIdx.x;
    const int tid = threadIdx.x;
    const int i = tid >> 2;  // output row 0..255
    const int p = tid & 3;   // K-split part 0..3

    __shared__ float hbuf[2][H_];

    // w[q] = W_hh[i][16q + 4p .. +3]   (chunk 4q+p of row i)
    float4 w[16];
    const float* wrow = W_hh + (size_t)i * H_ + p * 4;
#pragma unroll
    for (int q = 0; q < 16; ++q) w[q] = *(const float4*)(wrow + q * 16);

    if (tid < H_) hbuf[0][tid] = 0.0f;
    float hs = 0.0f;
    __syncthreads();

    int cur = 0;
    float xw_next = xw[(size_t)b * H_ + i];  // s = 0 (biases folded in)
    for (int s = 0; s < S_; ++s) {
        const float* hc = hbuf[cur] + p * 4;
        float acc0 = 0.f, acc1 = 0.f, acc2 = 0.f, acc3 = 0.f;
#pragma unroll
        for (int q = 0; q < 16; ++q) {
            const float4 hv = *(const float4*)(hc + q * 16);
            acc0 = fmaf(w[q].x, hv.x, acc0);
            acc1 = fmaf(w[q].y, hv.y, acc1);
            acc2 = fmaf(w[q].z, hv.z, acc2);
            acc3 = fmaf(w[q].w, hv.w, acc3);
        }
        float part = (acc0 + acc1) + (acc2 + acc3);
        part += __shfl_xor(part, 1);
        part += __shfl_xor(part, 2);
        float pre = xw_next + part;

        int sn = (s + 1 < S_) ? s + 1 : s;
        xw_next = xw[((size_t)sn * B_ + b) * H_ + i];  // prefetch next step

        float hn = fast_tanh(pre);
        if (p == 0) {
            hs += hn;
            hbuf[cur ^ 1][i] = hn;
        }
        __syncthreads();
        cur ^= 1;
    }
    if (p == 0) hsum_out[b * H_ + i] = hs;
}

// ---------------------------------------------------------------------------
// Kernel D: summed logits = hsum @ W_out^T + S*b_out, then log_softmax.
// ---------------------------------------------------------------------------
__global__ void out_kernel(const float* __restrict__ hsum,
                           const float* __restrict__ W_out,
                           const float* __restrict__ b_out,
                           float* __restrict__ out) {
    int b = threadIdx.x;
    if (b >= B_) return;
    float logits[C_];
#pragma unroll
    for (int c = 0; c < C_; ++c) {
        float acc = 0.0f;
        for (int k = 0; k < H_; ++k)
            acc = fmaf(hsum[b * H_ + k], W_out[c * H_ + k], acc);
        logits[c] = acc + (float)S_ * b_out[c];
    }
    float m = logits[0];
#pragma unroll
    for (int c = 1; c < C_; ++c) m = fmaxf(m, logits[c]);
    float sum = 0.0f;
#pragma unroll
    for (int c = 0; c < C_; ++c) sum += expf(logits[c] - m);
    float lse = logf(sum);
#pragma unroll
    for (int c = 0; c < C_; ++c) out[b * C_ + c] = logits[c] - m - lse;
}

// ---------------------------------------------------------------------------
extern "C" void kernel_launch(void* const* d_in, const int* in_sizes, int n_in,
                              void* d_out, int out_size, void* d_ws,
                              size_t ws_size, hipStream_t stream) {
    const int* idx = (const int*)d_in[0];
    const float* emb = (const float*)d_in[1];
    const float* W_ih = (const float*)d_in[2];
    const float* W_hh = (const float*)d_in[3];
    const float* b_ih = (const float*)d_in[4];
    const float* b_hh = (const float*)d_in[5];
    const float* W_out = (const float*)d_in[6];
    const float* b_out = (const float*)d_in[7];
    float* out = (float*)d_out;

    float* ws = (float*)d_ws;
    float* WT = ws;                                 // E*H      = 76800 floats
    float* xw = WT + E_ * H_;                       // S*B*H    = 8388608 floats
    float* hsum = xw + (size_t)S_ * B_ * H_;        // B*H      = 16384 floats

    hipLaunchKernelGGL(transpose_kernel, dim3((E_ * H_ + 255) / 256), dim3(256),
                       0, stream, W_ih, WT);
    hipLaunchKernelGGL(xw_kernel, dim3((S_ * B_) / 64), dim3(256), 0, stream,
                       idx, emb, WT, b_ih, b_hh, xw);
    hipLaunchKernelGGL(rnn_kernel, dim3(B_), dim3(1024), 0, stream, xw, W_hh,
                       hsum);
    hipLaunchKernelGGL(out_kernel, dim3(1), dim3(64), 0, stream, hsum, W_out,
                       b_out, out);
}

// Round 3
// 396.662 us; speedup vs baseline: 3.6687x; 1.3618x over previous
//
#include <hip/hip_runtime.h>
#include <stdint.h>

#define S_ 512
#define B_ 64
#define V_ 50000
#define E_ 300
#define H_ 256
#define C_ 5

typedef _Float16 h2_t __attribute__((ext_vector_type(2)));

// packed f16 dot with fp32 accumulate: c += a.x*w.x + a.y*w.y
__device__ __forceinline__ float fdot2(uint32_t a, uint32_t w, float c) {
#if __has_builtin(__builtin_amdgcn_fdot2)
    return __builtin_amdgcn_fdot2(__builtin_bit_cast(h2_t, a),
                                  __builtin_bit_cast(h2_t, w), c, false);
#else
    h2_t ha = __builtin_bit_cast(h2_t, a);
    h2_t hw = __builtin_bit_cast(h2_t, w);
    return fmaf((float)ha[1], (float)hw[1], fmaf((float)ha[0], (float)hw[0], c));
#endif
}

// v + (v rotated by CTRL within the 16-lane row) — pure VALU (DPP), no LDS pipe
template <int CTRL>
__device__ __forceinline__ float rra(float v) {
    int s = __builtin_amdgcn_update_dpp(0, __builtin_bit_cast(int, v), CTRL,
                                        0xF, 0xF, false);
    return v + __builtin_bit_cast(float, s);
}
// full sum over the 16-lane row (result in all 16 lanes)
__device__ __forceinline__ float reduce16(float v) {
    v = rra<0x128>(v);  // row_ror:8
    v = rra<0x124>(v);  // row_ror:4
    v = rra<0x122>(v);  // row_ror:2
    v = rra<0x121>(v);  // row_ror:1
    return v;
}

__device__ __forceinline__ float fast_tanh(float x) {
    x = fminf(9.5f, fmaxf(-9.5f, x));
    float e = __builtin_amdgcn_exp2f(x * 2.88539008177793f);  // 2*log2(e)
    return (e - 1.0f) * __builtin_amdgcn_rcpf(e + 1.0f);
}

// ---------------------------------------------------------------------------
// Kernel A: transpose W_ih (H,E) -> WT (E,H)
// ---------------------------------------------------------------------------
__global__ void transpose_kernel(const float* __restrict__ W_ih,
                                 float* __restrict__ WT) {
    int i = blockIdx.x * 256 + threadIdx.x;
    if (i < E_ * H_) {
        int e = i / H_;
        int h = i - e * H_;
        WT[i] = W_ih[h * E_ + e];
    }
}

// ---------------------------------------------------------------------------
// Kernel B: xw[s,b,h] = sum_e emb[idx[s,b],e]*W_ih[h,e] + b_ih[h] + b_hh[h]
// 512 blocks x 256 threads; block does 64 rows. Per-thread 8r x 8h tile:
// 32 FMA per ds_read_b128 -> VALU-bound (~32us floor).
// ---------------------------------------------------------------------------
__global__ __launch_bounds__(256, 2) void xw_kernel(
    const int* __restrict__ idx, const float* __restrict__ emb,
    const float* __restrict__ WT, const float* __restrict__ b_ih,
    const float* __restrict__ b_hh, float* __restrict__ xw) {
    __shared__ float xs[64 * E_];  // 76.8 KB
    const int base = blockIdx.x * 64;
    const int tid = threadIdx.x;
    const int rq = tid >> 5;  // 0..7  -> rows 8rq..8rq+7
    const int hq = tid & 31;  // 0..31 -> cols 8hq..8hq+7

    // stage 64 embedding rows; 300 floats = 75 float4 per row (1200B stride,
    // 16B-aligned)
    for (int t = tid; t < 64 * 75; t += 256) {
        int r = t / 75;
        int c = t - r * 75;
        float4 v = *(const float4*)(emb + (size_t)idx[base + r] * E_ + 4 * c);
        *(float4*)(xs + r * E_ + 4 * c) = v;
    }
    __syncthreads();

    float acc[8][8];
#pragma unroll
    for (int u = 0; u < 8; ++u)
#pragma unroll
        for (int j = 0; j < 8; ++j) acc[u][j] = 0.0f;

    for (int e = 0; e < E_; e += 4) {
        const float* wp = WT + e * H_ + 8 * hq;
        float wv[4][8];
#pragma unroll
        for (int q = 0; q < 4; ++q) {
            float4 aa = *(const float4*)(wp + q * H_);
            float4 bb = *(const float4*)(wp + q * H_ + 4);
            wv[q][0] = aa.x; wv[q][1] = aa.y; wv[q][2] = aa.z; wv[q][3] = aa.w;
            wv[q][4] = bb.x; wv[q][5] = bb.y; wv[q][6] = bb.z; wv[q][7] = bb.w;
        }
#pragma unroll
        for (int u = 0; u < 8; ++u) {
            const float4 xv = *(const float4*)(xs + (8 * rq + u) * E_ + e);
#pragma unroll
            for (int j = 0; j < 8; ++j) {
                float t = fmaf(xv.x, wv[0][j], acc[u][j]);
                t = fmaf(xv.y, wv[1][j], t);
                t = fmaf(xv.z, wv[2][j], t);
                acc[u][j] = fmaf(xv.w, wv[3][j], t);
            }
        }
    }

    float bias[8];
    {
        float4 ba = *(const float4*)(b_ih + 8 * hq);
        float4 bb = *(const float4*)(b_ih + 8 * hq + 4);
        float4 ca = *(const float4*)(b_hh + 8 * hq);
        float4 cb = *(const float4*)(b_hh + 8 * hq + 4);
        bias[0] = ba.x + ca.x; bias[1] = ba.y + ca.y;
        bias[2] = ba.z + ca.z; bias[3] = ba.w + ca.w;
        bias[4] = bb.x + cb.x; bias[5] = bb.y + cb.y;
        bias[6] = bb.z + cb.z; bias[7] = bb.w + cb.w;
    }
#pragma unroll
    for (int u = 0; u < 8; ++u) {
        float4 o0, o1;
        o0.x = acc[u][0] + bias[0]; o0.y = acc[u][1] + bias[1];
        o0.z = acc[u][2] + bias[2]; o0.w = acc[u][3] + bias[3];
        o1.x = acc[u][4] + bias[4]; o1.y = acc[u][5] + bias[5];
        o1.z = acc[u][6] + bias[6]; o1.w = acc[u][7] + bias[7];
        float* op = xw + (size_t)(base + 8 * rq + u) * H_ + 8 * hq;
        *(float4*)op = o0;
        *(float4*)(op + 4) = o1;
    }
}

// ---------------------------------------------------------------------------
// Kernel C: recurrence. 1 block (1024 thr) per batch element.
//   g = tid>>4 (0..63), p = tid&15: 16-way K-split, 4 rows/thread
//   rows {g, g+64, g+128, g+192}; k-chunk = [16p, 16p+16)
//   weights: 4 rows x 8 packed-f16 dwords = 32 VGPRs (register-resident)
//   h in LDS as f16, DE-INTERLEAVED 16B lines: even line 2p at byte 16p,
//   odd line 2p+1 at byte 256+16p  -> the wave's reads are 2-way bank
//   aliasing (free) instead of 4-way.
//   reduce over 16 k-lanes: 4x DPP row_ror adds (VALU, no LDS pipe)
//   lane p<4 owns row g+64p: tanh result select via 3 cndmask, b16 write.
//   xw prefetched 2 steps ahead (covers ~900cyc HBM latency).
// ---------------------------------------------------------------------------
__global__ __launch_bounds__(1024, 4) void rnn_kernel(
    const float* __restrict__ xw, const float* __restrict__ W_hh,
    float* __restrict__ hsum_out) {
    const int b = blockIdx.x;
    const int tid = threadIdx.x;
    const int g = tid >> 4;
    const int p = tid & 15;
    const int r_sel = p & 3;
    const int my_row = g + 64 * r_sel;

    __shared__ __attribute__((aligned(16))) unsigned short hb[2][256];

    // pack weights: wa[r][j] = f16x2( W[g+64r][16p+2j], W[g+64r][16p+2j+1] )
    uint32_t wa[4][8];
#pragma unroll
    for (int r = 0; r < 4; ++r) {
        const float* wr = W_hh + (size_t)(g + 64 * r) * H_ + 16 * p;
#pragma unroll
        for (int j = 0; j < 8; ++j) {
            float2 wv = *(const float2*)(wr + 2 * j);
            h2_t hh;
            hh[0] = (_Float16)wv.x;
            hh[1] = (_Float16)wv.y;
            wa[r][j] = __builtin_bit_cast(uint32_t, hh);
        }
    }

    // de-interleaved write index for h[my_row]
    const int lsel = my_row >> 3;                    // 16B line 0..31
    const int slot = (lsel >> 1) + 16 * (lsel & 1);  // even->0..15, odd->16..31
    const int widx = slot * 8 + (my_row & 7);

    if (tid < 256) hb[0][tid] = 0;  // f16 zero bits
    float hs = 0.0f;
    __syncthreads();

    const float* xwb = xw + b * H_ + my_row;  // step stride B_*H_
    float xw0 = xwb[0];
    float xw1 = xwb[B_ * H_];

#define RNN_BODY(CUR, SB, XWREG)                                            \
    {                                                                       \
        const uint4 ua = *(const uint4*)&hb[CUR][8 * p];                    \
        const uint4 ub = *(const uint4*)&hb[CUR][128 + 8 * p];              \
        const int sp = ((SB) + 2 < S_) ? (SB) + 2 : S_ - 1;                 \
        const float xwn = xwb[sp * (B_ * H_)];                              \
        float a0 = 0.f, a1 = 0.f, a2 = 0.f, a3 = 0.f;                       \
        a0 = fdot2(ua.x, wa[0][0], a0); a1 = fdot2(ua.x, wa[1][0], a1);     \
        a2 = fdot2(ua.x, wa[2][0], a2); a3 = fdot2(ua.x, wa[3][0], a3);     \
        a0 = fdot2(ua.y, wa[0][1], a0); a1 = fdot2(ua.y, wa[1][1], a1);     \
        a2 = fdot2(ua.y, wa[2][1], a2); a3 = fdot2(ua.y, wa[3][1], a3);     \
        a0 = fdot2(ua.z, wa[0][2], a0); a1 = fdot2(ua.z, wa[1][2], a1);     \
        a2 = fdot2(ua.z, wa[2][2], a2); a3 = fdot2(ua.z, wa[3][2], a3);     \
        a0 = fdot2(ua.w, wa[0][3], a0); a1 = fdot2(ua.w, wa[1][3], a1);     \
        a2 = fdot2(ua.w, wa[2][3], a2); a3 = fdot2(ua.w, wa[3][3], a3);     \
        a0 = fdot2(ub.x, wa[0][4], a0); a1 = fdot2(ub.x, wa[1][4], a1);     \
        a2 = fdot2(ub.x, wa[2][4], a2); a3 = fdot2(ub.x, wa[3][4], a3);     \
        a0 = fdot2(ub.y, wa[0][5], a0); a1 = fdot2(ub.y, wa[1][5], a1);     \
        a2 = fdot2(ub.y, wa[2][5], a2); a3 = fdot2(ub.y, wa[3][5], a3);     \
        a0 = fdot2(ub.z, wa[0][6], a0); a1 = fdot2(ub.z, wa[1][6], a1);     \
        a2 = fdot2(ub.z, wa[2][6], a2); a3 = fdot2(ub.z, wa[3][6], a3);     \
        a0 = fdot2(ub.w, wa[0][7], a0); a1 = fdot2(ub.w, wa[1][7], a1);     \
        a2 = fdot2(ub.w, wa[2][7], a2); a3 = fdot2(ub.w, wa[3][7], a3);     \
        a0 = reduce16(a0); a1 = reduce16(a1);                               \
        a2 = reduce16(a2); a3 = reduce16(a3);                               \
        float v = a0;                                                       \
        v = (r_sel == 1) ? a1 : v;                                          \
        v = (r_sel == 2) ? a2 : v;                                          \
        v = (r_sel == 3) ? a3 : v;                                          \
        float hn = fast_tanh(XWREG + v);                                    \
        hs += hn;                                                           \
        if (p < 4)                                                          \
            hb[CUR ^ 1][widx] =                                             \
                __builtin_bit_cast(unsigned short, (_Float16)hn);           \
        XWREG = xwn;                                                        \
        __syncthreads();                                                    \
    }

    for (int s = 0; s < S_; s += 2) {
        RNN_BODY(0, s, xw0)
        RNN_BODY(1, s + 1, xw1)
    }
#undef RNN_BODY

    if (p < 4) hsum_out[b * H_ + my_row] = hs;
}

// ---------------------------------------------------------------------------
// Kernel D: summed logits = hsum @ W_out^T + S*b_out, then log_softmax.
// ---------------------------------------------------------------------------
__global__ void out_kernel(const float* __restrict__ hsum,
                           const float* __restrict__ W_out,
                           const float* __restrict__ b_out,
                           float* __restrict__ out) {
    int b = threadIdx.x;
    if (b >= B_) return;
    float logits[C_];
#pragma unroll
    for (int c = 0; c < C_; ++c) {
        float acc = 0.0f;
        for (int k = 0; k < H_; ++k)
            acc = fmaf(hsum[b * H_ + k], W_out[c * H_ + k], acc);
        logits[c] = acc + (float)S_ * b_out[c];
    }
    float m = logits[0];
#pragma unroll
    for (int c = 1; c < C_; ++c) m = fmaxf(m, logits[c]);
    float sum = 0.0f;
#pragma unroll
    for (int c = 0; c < C_; ++c) sum += expf(logits[c] - m);
    float lse = logf(sum);
#pragma unroll
    for (int c = 0; c < C_; ++c) out[b * C_ + c] = logits[c] - m - lse;
}

// ---------------------------------------------------------------------------
extern "C" void kernel_launch(void* const* d_in, const int* in_sizes, int n_in,
                              void* d_out, int out_size, void* d_ws,
                              size_t ws_size, hipStream_t stream) {
    const int* idx = (const int*)d_in[0];
    const float* emb = (const float*)d_in[1];
    const float* W_ih = (const float*)d_in[2];
    const float* W_hh = (const float*)d_in[3];
    const float* b_ih = (const float*)d_in[4];
    const float* b_hh = (const float*)d_in[5];
    const float* W_out = (const float*)d_in[6];
    const float* b_out = (const float*)d_in[7];
    float* out = (float*)d_out;

    float* ws = (float*)d_ws;
    float* WT = ws;                           // E*H
    float* xw = WT + E_ * H_;                 // S*B*H
    float* hsum = xw + (size_t)S_ * B_ * H_;  // B*H

    hipLaunchKernelGGL(transpose_kernel, dim3((E_ * H_ + 255) / 256), dim3(256),
                       0, stream, W_ih, WT);
    hipLaunchKernelGGL(xw_kernel, dim3((S_ * B_) / 64), dim3(256), 0, stream,
                       idx, emb, WT, b_ih, b_hh, xw);
    hipLaunchKernelGGL(rnn_kernel, dim3(B_), dim3(1024), 0, stream, xw, W_hh,
                       hsum);
    hipLaunchKernelGGL(out_kernel, dim3(1), dim3(64), 0, stream, hsum, W_out,
                       b_out, out);
}